// Round 5
// baseline (212.356 us; speedup 1.0000x reference)
//
#include <hip/hip_runtime.h>
#include <hip/hip_bf16.h>

typedef __attribute__((ext_vector_type(8))) short short8v;
typedef __attribute__((ext_vector_type(4))) float floatx4;

#define B_ROWS 2048
#define K_DIM  1024
#define N_CON  64
#define TWO_E  256
#define E_DIM  128
#define BM     128
#define BK     64
#define NT     16
#define LDSA_BYTES (BM * BK * 2)              // 16384 per buffer
#define SMEM_BYTES (2 * LDSA_BYTES)           // 32768 (A double-buffer)
#define EMB_ELEMS 16777216ULL                 // 2048*64*128
#define WT_BYTES  33554432ULL                 // 64*256*1024*2
#define XB_BYTES  4194304ULL                  // 2048*1024*2

// fp32 -> bf16 bit pattern via proven __float2bfloat16 + memcpy punning.
static __device__ inline unsigned short bf16bits(float f) {
    __hip_bfloat16 h = __float2bfloat16(f);
    unsigned short u;
    __builtin_memcpy(&u, &h, 2);
    return u;
}

// Async 16B global->LDS DMA. LDS dest = wave-uniform base + lane*16 (m104).
static __device__ inline void dma16(const void* g, void* l) {
    __builtin_amdgcn_global_load_lds(
        (const __attribute__((address_space(1))) unsigned int*)g,
        (__attribute__((address_space(3))) unsigned int*)l,
        16, 0, 0);
}

// ---------------------------------------------------------------------------
// Pre-pass (unchanged, verified): W[n][k][o] fp32 -> Wt[n][o][k] bf16;
// x fp32 -> xb bf16. Grid (4,16,64).
// ---------------------------------------------------------------------------
__global__ void __launch_bounds__(256) prep(const float* __restrict__ W,
                                            const float* __restrict__ x,
                                            unsigned short* __restrict__ Wt,
                                            unsigned short* __restrict__ xb) {
    __shared__ unsigned int lds2[64 * 36];   // [o][kpair], padded rows
    const int tid = threadIdx.x;
    const int ot = blockIdx.x, ktile = blockIdx.y, n = blockIdx.z;
    const float* src = W + ((size_t)n * K_DIM + (size_t)ktile * 64) * TWO_E + ot * 64;
    unsigned short* dst = Wt + ((size_t)n * TWO_E + (size_t)ot * 64) * K_DIM + ktile * 64;

    const int kp = tid >> 4;
    const int c  = (tid & 15) * 4;
#pragma unroll
    for (int it = 0; it < 2; ++it) {
        const int k0 = it * 32 + kp * 2;
        floatx4 r0 = *(const floatx4*)&src[(size_t)k0 * TWO_E + c];
        floatx4 r1 = *(const floatx4*)&src[(size_t)(k0 + 1) * TWO_E + c];
#pragma unroll
        for (int j = 0; j < 4; ++j) {
            unsigned int d = (unsigned int)bf16bits(r0[j]) |
                             ((unsigned int)bf16bits(r1[j]) << 16);
            lds2[(c + j) * 36 + it * 16 + kp] = d;
        }
    }
    __syncthreads();
#pragma unroll
    for (int it = 0; it < 2; ++it) {
        int q = it * 256 + tid;
        int o = q >> 3, kc = q & 7;
        short8v v = *(short8v*)&lds2[o * 36 + kc * 4];
        *(short8v*)&dst[(size_t)o * K_DIM + kc * 8] = v;
    }

    const int bid = blockIdx.x + blockIdx.y * 4 + blockIdx.z * 64;
    const size_t base = (size_t)bid * 512 + (size_t)tid * 2;
    unsigned int d = (unsigned int)bf16bits(x[base]) |
                     ((unsigned int)bf16bits(x[base + 1]) << 16);
    ((unsigned int*)xb)[base >> 1] = d;
}

// ---------------------------------------------------------------------------
// Fused GEMM, round-5 structure:
//   B (weights) has ZERO cross-wave reuse -> load direct global->VGPR
//   (8 short8v/wave/tile from L2-resident Wt; deletes 32KB/WG-tile of LDS
//   writes + 8 ds_reads/wave and 8 of 12 dma from the barrier drain chain).
//   A (x) has 4x cross-wave reuse -> stays in LDS, now DOUBLE-buffered
//   (2x16KB): stage A[t+1] during compute of t => ONE barrier per K-tile
//   (16 vs 32), and the vmcnt(0) drain at the barrier covers only 4 dma
//   issued a full tile earlier.
//   B loads issue BEFORE the A-dma each tile: vmcnt is oldest-first, so
//   per-register waits on B leave the A staging in flight.
//   Geometry unchanged from r4: 256 thr / 4 waves, wave-tile 128x64,
//   acc[8][4]; T1 bijective XCD swizzle (FETCH 135->49 MB, verified).
// ---------------------------------------------------------------------------
__global__ void __launch_bounds__(256, 2)
concept5(const unsigned short* __restrict__ xb,   // bf16 [2048][1024]
         const unsigned short* __restrict__ Wt,   // bf16 [n][o][k]
         const float* __restrict__ bc,
         const float* __restrict__ wp,
         const float* __restrict__ bp,
         float* __restrict__ out) {
    __shared__ __align__(16) char smem[SMEM_BYTES];

    const int tid  = threadIdx.x;
    const int wave = tid >> 6;        // 0..3 = o group
    const int lane = tid & 63;
    const int lg   = lane >> 4;       // quad 0..3
    const int l15  = lane & 15;
    const int og   = wave;

    // T1 bijective XCD swizzle over 1024 WGs (1024 % 8 == 0).
    const int lin = blockIdx.y * 16 + blockIdx.x;
    const int nid = (lin & 7) * 128 + (lin >> 3);
    const int rb  = nid & 15;         // 0..15 (128 rows each)
    const int n   = nid >> 4;         // 0..63

    int otile[4];
#pragma unroll
    for (int oi = 0; oi < 4; ++oi) otile[oi] = og * 32 + (oi & 1) * 16 + (oi & 2) * 64;

    floatx4 acc[8][4];
#pragma unroll
    for (int mi = 0; mi < 8; ++mi)
#pragma unroll
        for (int oi = 0; oi < 4; ++oi) acc[mi][oi] = (floatx4){0.f, 0.f, 0.f, 0.f};

    const unsigned short* xrow = xb + (size_t)rb * BM * K_DIM;
    // Per-lane B base pointers: row (otile[oi]+l15), k-offset lg*8 folded in.
    const unsigned short* wb[4];
#pragma unroll
    for (int oi = 0; oi < 4; ++oi)
        wb[oi] = Wt + ((size_t)n * TWO_E + otile[oi] + l15) * K_DIM + lg * 8;

    // A-read swizzle offsets (XOR layout matches the dma source swizzle)
    const int sw0 = ((lg) ^ (l15 & 7)) * 16;
    const int sw1 = ((4 + lg) ^ (l15 & 7)) * 16;
    const int abase = l15 * 128;

    // ---- prologue: stage A tile 0 into buf0 (4 dma/thread-group) ----
#pragma unroll
    for (int it = 0; it < 4; ++it) {
        int c = it * 4 + wave;
        int s = c * 64 + lane;
        int r = s >> 3, g = s & 7;
        dma16(xrow + (size_t)r * K_DIM + ((g ^ (r & 7)) * 8), smem + c * 1024);
    }
    __syncthreads();   // drains vmcnt(0): A[0] resident

#pragma unroll 1
    for (int t = 0; t < NT; ++t) {
        const int kt = t * BK;
        char* ldsR = smem + (t & 1) * LDSA_BYTES;

        // ---- B fragments: direct global->reg (issued FIRST) ----
        short8v bfr[4][2];
#pragma unroll
        for (int oi = 0; oi < 4; ++oi)
#pragma unroll
            for (int ks = 0; ks < 2; ++ks)
                bfr[oi][ks] = *(const short8v*)(wb[oi] + kt + ks * 32);

        // ---- stage A[t+1] into the other buffer (after B: vmcnt order) ----
        if (t + 1 < NT) {
            char* ldsW = smem + ((t + 1) & 1) * LDSA_BYTES;
            const int ktn = kt + BK;
#pragma unroll
            for (int it = 0; it < 4; ++it) {
                int c = it * 4 + wave;
                int s = c * 64 + lane;
                int r = s >> 3, g = s & 7;
                dma16(xrow + (size_t)r * K_DIM + ktn + ((g ^ (r & 7)) * 8),
                      ldsW + c * 1024);
            }
        }

        // ---- compute: mi-outer, A fragment read once, B from regs ----
#pragma unroll
        for (int mi = 0; mi < 8; ++mi) {
            short8v a0 = *(const short8v*)(ldsR + abase + mi * 2048 + sw0);
            short8v a1 = *(const short8v*)(ldsR + abase + mi * 2048 + sw1);
#pragma unroll
            for (int oi = 0; oi < 4; ++oi) {
                acc[mi][oi] = __builtin_amdgcn_mfma_f32_16x16x32_bf16(
                    a0, bfr[oi][0], acc[mi][oi], 0, 0, 0);
                acc[mi][oi] = __builtin_amdgcn_mfma_f32_16x16x32_bf16(
                    a1, bfr[oi][1], acc[mi][oi], 0, 0, 0);
            }
        }

        __syncthreads();   // one barrier/tile: A[t+1] landed, A[t] reads done
    }

    // ---- epilogue (fp32, unchanged math) ----
    float biasf[4], wpf[4];
#pragma unroll
    for (int oi = 0; oi < 4; ++oi) {
        int o = otile[oi] + l15;
        biasf[oi] = bc[n * TWO_E + o];
        wpf[oi]  = wp[o];
    }
#pragma unroll
    for (int mi = 0; mi < 8; ++mi)
#pragma unroll
        for (int oi = 0; oi < 4; ++oi)
#pragma unroll
            for (int j = 0; j < 4; ++j) {
                float v = acc[mi][oi][j] + biasf[oi];
                acc[mi][oi][j] = v >= 0.f ? v : 0.01f * v;   // LeakyReLU
            }

    float* partial = (float*)smem;            // [128][4]
    float* pv      = (float*)(smem + 2048);   // [128]

#pragma unroll
    for (int mi = 0; mi < 8; ++mi)
#pragma unroll
        for (int j = 0; j < 4; ++j) {
            float ps = 0.f;
#pragma unroll
            for (int oi = 0; oi < 4; ++oi) ps += acc[mi][oi][j] * wpf[oi];
            ps += __shfl_xor(ps, 1);
            ps += __shfl_xor(ps, 2);
            ps += __shfl_xor(ps, 4);
            ps += __shfl_xor(ps, 8);
            if (l15 == 0) partial[(mi * 16 + lg * 4 + j) * 4 + og] = ps;
        }
    __syncthreads();

    if (tid < 128) {
        float s = partial[tid * 4] + partial[tid * 4 + 1] + partial[tid * 4 + 2] +
                  partial[tid * 4 + 3] + bp[0];
        float p = 1.f / (1.f + __expf(-s));
        pv[tid] = p;
        size_t bi = (size_t)rb * BM + tid;
        out[EMB_ELEMS + bi * N_CON + n] = p;    // c_pred
    }
    __syncthreads();

#pragma unroll
    for (int mi = 0; mi < 8; ++mi)
#pragma unroll
        for (int oi = 0; oi < 2; ++oi)
#pragma unroll
            for (int j = 0; j < 4; ++j) {
                int row = mi * 16 + lg * 4 + j;
                int e = og * 32 + oi * 16 + l15;
                float p = pv[row];
                float v = acc[mi][oi][j] * p + acc[mi][oi + 2][j] * (1.f - p);
                size_t bi = (size_t)rb * BM + row;
                out[(bi * N_CON + n) * E_DIM + e] = v;
            }
}

// ---------------------------------------------------------------------------
// Fallback (no workspace): round-0 single-buffered fp32-staging kernel.
// ---------------------------------------------------------------------------
__global__ void __launch_bounds__(512, 4)
concept_fallback(const float* __restrict__ x,
                 const float* __restrict__ Wc,
                 const float* __restrict__ bc,
                 const float* __restrict__ wp,
                 const float* __restrict__ bp,
                 float* __restrict__ out) {
    __shared__ __align__(16) char smem[49152];
    char* ldsA = smem;
    char* ldsB = smem + 16384;

    const int tid  = threadIdx.x;
    const int wave = tid >> 6;
    const int lane = tid & 63;
    const int lg   = lane >> 4;
    const int l15  = lane & 15;
    const int h    = wave >> 2;
    const int og   = wave & 3;
    const int rb = blockIdx.x;
    const int n  = blockIdx.y;

    int otile[4];
#pragma unroll
    for (int oi = 0; oi < 4; ++oi) otile[oi] = og * 32 + (oi & 1) * 16 + (oi & 2) * 64;

    floatx4 acc[4][4];
#pragma unroll
    for (int mi = 0; mi < 4; ++mi)
#pragma unroll
        for (int oi = 0; oi < 4; ++oi) acc[mi][oi] = (floatx4){0.f, 0.f, 0.f, 0.f};

    const float* xg = x + (size_t)rb * BM * K_DIM;
    const float* wg = Wc + (size_t)n * K_DIM * TWO_E;

    for (int kt = 0; kt < K_DIM; kt += BK) {
#pragma unroll
        for (int it = 0; it < 2; ++it) {
            int s = it * 512 + tid;
            int r = s >> 3, g = s & 7;
            const float* p = xg + (size_t)r * K_DIM + kt + ((g ^ (r & 7)) * 8);
            floatx4 v0 = *(const floatx4*)p, v1 = *(const floatx4*)(p + 4);
            short8v b;
            b[0] = (short)bf16bits(v0[0]); b[1] = (short)bf16bits(v0[1]);
            b[2] = (short)bf16bits(v0[2]); b[3] = (short)bf16bits(v0[3]);
            b[4] = (short)bf16bits(v1[0]); b[5] = (short)bf16bits(v1[1]);
            b[6] = (short)bf16bits(v1[2]); b[7] = (short)bf16bits(v1[3]);
            *(short8v*)(ldsA + s * 16) = b;
        }
#pragma unroll
        for (int it = 0; it < 4; ++it) {
            int s = it * 512 + tid;
            int r = s >> 3, g = s & 7;
            int k0 = kt + (g ^ (r & 7)) * 8;
            short8v b;
#pragma unroll
            for (int j = 0; j < 8; ++j)
                b[j] = (short)bf16bits(wg[(size_t)(k0 + j) * TWO_E + r]);
            *(short8v*)(ldsB + s * 16) = b;
        }
        __syncthreads();

#pragma unroll
        for (int ks = 0; ks < 2; ++ks) {
            const int sw = ((ks * 4 + lg) ^ (l15 & 7)) * 16;
            short8v af[4], bfr[4];
#pragma unroll
            for (int mi = 0; mi < 4; ++mi)
                af[mi] = *(const short8v*)(ldsA + (h * 64 + mi * 16 + l15) * 128 + sw);
#pragma unroll
            for (int oi = 0; oi < 4; ++oi)
                bfr[oi] = *(const short8v*)(ldsB + (otile[oi] + l15) * 128 + sw);
#pragma unroll
            for (int mi = 0; mi < 4; ++mi)
#pragma unroll
                for (int oi = 0; oi < 4; ++oi)
                    acc[mi][oi] = __builtin_amdgcn_mfma_f32_16x16x32_bf16(
                        af[mi], bfr[oi], acc[mi][oi], 0, 0, 0);
        }
        __syncthreads();
    }

    float biasf[4], wpf[4];
#pragma unroll
    for (int oi = 0; oi < 4; ++oi) {
        int o = otile[oi] + l15;
        biasf[oi] = bc[n * TWO_E + o];
        wpf[oi]  = wp[o];
    }
#pragma unroll
    for (int mi = 0; mi < 4; ++mi)
#pragma unroll
        for (int oi = 0; oi < 4; ++oi)
#pragma unroll
            for (int j = 0; j < 4; ++j) {
                float v = acc[mi][oi][j] + biasf[oi];
                acc[mi][oi][j] = v >= 0.f ? v : 0.01f * v;
            }

    float* partial = (float*)smem;
    float* pv      = (float*)(smem + 2048);

#pragma unroll
    for (int mi = 0; mi < 4; ++mi)
#pragma unroll
        for (int j = 0; j < 4; ++j) {
            float ps = 0.f;
#pragma unroll
            for (int oi = 0; oi < 4; ++oi) ps += acc[mi][oi][j] * wpf[oi];
            ps += __shfl_xor(ps, 1);
            ps += __shfl_xor(ps, 2);
            ps += __shfl_xor(ps, 4);
            ps += __shfl_xor(ps, 8);
            if (l15 == 0) partial[(h * 64 + mi * 16 + lg * 4 + j) * 4 + og] = ps;
        }
    __syncthreads();

    if (tid < 128) {
        float s = partial[tid * 4] + partial[tid * 4 + 1] + partial[tid * 4 + 2] +
                  partial[tid * 4 + 3] + bp[0];
        float p = 1.f / (1.f + __expf(-s));
        pv[tid] = p;
        size_t bi = (size_t)rb * BM + tid;
        out[EMB_ELEMS + bi * N_CON + n] = p;
    }
    __syncthreads();

#pragma unroll
    for (int mi = 0; mi < 4; ++mi)
#pragma unroll
        for (int oi = 0; oi < 2; ++oi)
#pragma unroll
            for (int j = 0; j < 4; ++j) {
                int row = h * 64 + mi * 16 + lg * 4 + j;
                int e = og * 32 + oi * 16 + l15;
                float p = pv[row];
                float v = acc[mi][oi][j] * p + acc[mi][oi + 2][j] * (1.f - p);
                size_t bi = (size_t)rb * BM + row;
                out[(bi * N_CON + n) * E_DIM + e] = v;
            }
}

extern "C" void kernel_launch(void* const* d_in, const int* in_sizes, int n_in,
                              void* d_out, int out_size, void* d_ws, size_t ws_size,
                              hipStream_t stream) {
    const float* x  = (const float*)d_in[0];
    const float* Wc = (const float*)d_in[1];
    const float* bc = (const float*)d_in[2];
    const float* wp = (const float*)d_in[3];
    const float* bp = (const float*)d_in[4];
    float* out = (float*)d_out;

    if (ws_size >= WT_BYTES + XB_BYTES) {
        unsigned short* Wt = (unsigned short*)d_ws;
        unsigned short* xb = (unsigned short*)((char*)d_ws + WT_BYTES);
        prep<<<dim3(4, 16, 64), 256, 0, stream>>>(Wc, x, Wt, xb);
        concept5<<<dim3(16, 64), 256, 0, stream>>>(xb, Wt, bc, wp, bp, out);
    } else {
        concept_fallback<<<dim3(16, 64), 512, 0, stream>>>(
            x, Wc, bc, wp, bp, out);
    }
}

// Round 6
// 210.970 us; speedup vs baseline: 1.0066x; 1.0066x over previous
//
#include <hip/hip_runtime.h>
#include <hip/hip_bf16.h>

typedef __attribute__((ext_vector_type(8))) short short8v;
typedef __attribute__((ext_vector_type(4))) float floatx4;

#define B_ROWS 2048
#define K_DIM  1024
#define N_CON  64
#define TWO_E  256
#define E_DIM  128
#define BM     128
#define BK     64
#define NT     16
#define LDSA_BYTES (BM * BK * 2)              // 16384 per buffer
#define SMEM_BYTES (2 * LDSA_BYTES)           // 32768 (A double-buffer)
#define EMB_ELEMS 16777216ULL                 // 2048*64*128
#define WT_BYTES  33554432ULL                 // 64*256*1024*2
#define XB_BYTES  4194304ULL                  // 2048*1024*2

// fp32 -> bf16 bit pattern via proven __float2bfloat16 + memcpy punning.
static __device__ inline unsigned short bf16bits(float f) {
    __hip_bfloat16 h = __float2bfloat16(f);
    unsigned short u;
    __builtin_memcpy(&u, &h, 2);
    return u;
}

// Async 16B global->LDS DMA. LDS dest = wave-uniform base + lane*16 (m104).
static __device__ inline void dma16(const void* g, void* l) {
    __builtin_amdgcn_global_load_lds(
        (const __attribute__((address_space(1))) unsigned int*)g,
        (__attribute__((address_space(3))) unsigned int*)l,
        16, 0, 0);
}

// ---------------------------------------------------------------------------
// Pre-pass: W[n][k][o] fp32 -> Wt[n][o][k] bf16; x fp32 -> xb bf16.
// Grid (4,16,64). r6 change: LDS pad stride 36 -> 33 dwords. With stride 36
// the k-pair dword writes hit bank ((c+j)*36+kp)&31, and 36c mod 32 spans
// only {0,16} over c -> 8-way write conflict. Stride 33 gives bank
// (c+j+kp+j*32..)&31 = bijective over the wave -> conflict-free.
// ---------------------------------------------------------------------------
__global__ void __launch_bounds__(256) prep(const float* __restrict__ W,
                                            const float* __restrict__ x,
                                            unsigned short* __restrict__ Wt,
                                            unsigned short* __restrict__ xb) {
    __shared__ unsigned int lds2[64 * 33];   // [o][kpair], 33-dword rows
    const int tid = threadIdx.x;
    const int ot = blockIdx.x, ktile = blockIdx.y, n = blockIdx.z;
    const float* src = W + ((size_t)n * K_DIM + (size_t)ktile * 64) * TWO_E + ot * 64;
    unsigned short* dst = Wt + ((size_t)n * TWO_E + (size_t)ot * 64) * K_DIM + ktile * 64;

    const int kp = tid >> 4;
    const int c  = (tid & 15) * 4;
#pragma unroll
    for (int it = 0; it < 2; ++it) {
        const int k0 = it * 32 + kp * 2;
        floatx4 r0 = *(const floatx4*)&src[(size_t)k0 * TWO_E + c];
        floatx4 r1 = *(const floatx4*)&src[(size_t)(k0 + 1) * TWO_E + c];
#pragma unroll
        for (int j = 0; j < 4; ++j) {
            unsigned int d = (unsigned int)bf16bits(r0[j]) |
                             ((unsigned int)bf16bits(r1[j]) << 16);
            lds2[(c + j) * 33 + it * 16 + kp] = d;
        }
    }
    __syncthreads();
#pragma unroll
    for (int it = 0; it < 2; ++it) {
        int q = it * 256 + tid;
        int o = q >> 3, kc = q & 7;
        short8v v = *(short8v*)&lds2[o * 33 + kc * 4];
        *(short8v*)&dst[(size_t)o * K_DIM + kc * 8] = v;
    }

    const int bid = blockIdx.x + blockIdx.y * 4 + blockIdx.z * 64;
    const size_t base = (size_t)bid * 512 + (size_t)tid * 2;
    unsigned int d = (unsigned int)bf16bits(x[base]) |
                     ((unsigned int)bf16bits(x[base + 1]) << 16);
    ((unsigned int*)xb)[base >> 1] = d;
}

// ---------------------------------------------------------------------------
// Fused GEMM, round-6 structure = round-5 + B register double-buffering.
//   B (zero cross-wave reuse): direct global->VGPR, but PREFETCHED one tile
//   ahead into named ping-pong register sets (rule #20: no runtime-indexed
//   reg arrays). Tile t computes from fragments loaded at t-1 — already
//   drained by the previous __syncthreads -> ZERO VMEM wait on the compute
//   path (r5 exposed ~500 cy/tile by loading and consuming in-tile).
//   A (4x cross-wave reuse): LDS double-buffered, one barrier per tile.
//   Geometry: 256 thr / 4 waves, wave-tile 128x64, acc[8][4]; T1 bijective
//   XCD swizzle (FETCH 135->49 MB verified rounds 1-4).
// ---------------------------------------------------------------------------
__global__ void __launch_bounds__(256, 2)
concept6(const unsigned short* __restrict__ xb,   // bf16 [2048][1024]
         const unsigned short* __restrict__ Wt,   // bf16 [n][o][k]
         const float* __restrict__ bc,
         const float* __restrict__ wp,
         const float* __restrict__ bp,
         float* __restrict__ out) {
    __shared__ __align__(16) char smem[SMEM_BYTES];

    const int tid  = threadIdx.x;
    const int wave = tid >> 6;        // 0..3 = o group
    const int lane = tid & 63;
    const int lg   = lane >> 4;       // quad 0..3
    const int l15  = lane & 15;
    const int og   = wave;

    // T1 bijective XCD swizzle over 1024 WGs (1024 % 8 == 0).
    const int lin = blockIdx.y * 16 + blockIdx.x;
    const int nid = (lin & 7) * 128 + (lin >> 3);
    const int rb  = nid & 15;         // 0..15 (128 rows each)
    const int n   = nid >> 4;         // 0..63

    int otile[4];
#pragma unroll
    for (int oi = 0; oi < 4; ++oi) otile[oi] = og * 32 + (oi & 1) * 16 + (oi & 2) * 64;

    floatx4 acc[8][4];
#pragma unroll
    for (int mi = 0; mi < 8; ++mi)
#pragma unroll
        for (int oi = 0; oi < 4; ++oi) acc[mi][oi] = (floatx4){0.f, 0.f, 0.f, 0.f};

    const unsigned short* xrow = xb + (size_t)rb * BM * K_DIM;
    const unsigned short* wb[4];
#pragma unroll
    for (int oi = 0; oi < 4; ++oi)
        wb[oi] = Wt + ((size_t)n * TWO_E + otile[oi] + l15) * K_DIM + lg * 8;

    const int sw0 = ((lg) ^ (l15 & 7)) * 16;
    const int sw1 = ((4 + lg) ^ (l15 & 7)) * 16;
    const int abase = l15 * 128;

    // ---- prologue: stage A[0] (dma) and load B[0] into regs ----
#pragma unroll
    for (int it = 0; it < 4; ++it) {
        int c = it * 4 + wave;
        int s = c * 64 + lane;
        int r = s >> 3, g = s & 7;
        dma16(xrow + (size_t)r * K_DIM + ((g ^ (r & 7)) * 8), smem + c * 1024);
    }
    short8v bA[4][2], bB[4][2];
#pragma unroll
    for (int oi = 0; oi < 4; ++oi)
#pragma unroll
        for (int ks = 0; ks < 2; ++ks)
            bA[oi][ks] = *(const short8v*)(wb[oi] + ks * 32);
    __syncthreads();   // drains vmcnt(0): A[0] in LDS, B[0] in regs

    // Tile body: prefetch B[t+1]->NXT, stage A[t+1]->other LDS buf,
    // compute tile t from CUR + ldsR, then one barrier.
#define TILE_BODY(T, CUR, NXT)                                                \
    {                                                                         \
        const int t_ = (T);                                                   \
        if (t_ + 1 < NT) {                                                    \
            const int ktn = (t_ + 1) * BK;                                    \
            _Pragma("unroll")                                                 \
            for (int oi = 0; oi < 4; ++oi) {                                  \
                NXT[oi][0] = *(const short8v*)(wb[oi] + ktn);                  \
                NXT[oi][1] = *(const short8v*)(wb[oi] + ktn + 32);             \
            }                                                                 \
            char* ldsW = smem + ((t_ + 1) & 1) * LDSA_BYTES;                  \
            _Pragma("unroll")                                                 \
            for (int it = 0; it < 4; ++it) {                                  \
                int c = it * 4 + wave;                                        \
                int s = c * 64 + lane;                                        \
                int r = s >> 3, g = s & 7;                                    \
                dma16(xrow + (size_t)r * K_DIM + ktn + ((g ^ (r & 7)) * 8),   \
                      ldsW + c * 1024);                                       \
            }                                                                 \
        }                                                                     \
        char* ldsR = smem + (t_ & 1) * LDSA_BYTES;                            \
        _Pragma("unroll")                                                     \
        for (int mi = 0; mi < 8; ++mi) {                                      \
            short8v a0 = *(const short8v*)(ldsR + abase + mi * 2048 + sw0);   \
            short8v a1 = *(const short8v*)(ldsR + abase + mi * 2048 + sw1);   \
            _Pragma("unroll")                                                 \
            for (int oi = 0; oi < 4; ++oi) {                                  \
                acc[mi][oi] = __builtin_amdgcn_mfma_f32_16x16x32_bf16(        \
                    a0, CUR[oi][0], acc[mi][oi], 0, 0, 0);                    \
                acc[mi][oi] = __builtin_amdgcn_mfma_f32_16x16x32_bf16(        \
                    a1, CUR[oi][1], acc[mi][oi], 0, 0, 0);                    \
            }                                                                 \
        }                                                                     \
        __syncthreads();                                                      \
    }

#pragma unroll 1
    for (int tp = 0; tp < NT / 2; ++tp) {
        TILE_BODY(tp * 2,     bA, bB)
        TILE_BODY(tp * 2 + 1, bB, bA)
    }
#undef TILE_BODY

    // ---- epilogue (fp32, unchanged math) ----
    float biasf[4], wpf[4];
#pragma unroll
    for (int oi = 0; oi < 4; ++oi) {
        int o = otile[oi] + l15;
        biasf[oi] = bc[n * TWO_E + o];
        wpf[oi]  = wp[o];
    }
#pragma unroll
    for (int mi = 0; mi < 8; ++mi)
#pragma unroll
        for (int oi = 0; oi < 4; ++oi)
#pragma unroll
            for (int j = 0; j < 4; ++j) {
                float v = acc[mi][oi][j] + biasf[oi];
                acc[mi][oi][j] = v >= 0.f ? v : 0.01f * v;   // LeakyReLU
            }

    float* partial = (float*)smem;            // [128][4]
    float* pv      = (float*)(smem + 2048);   // [128]

#pragma unroll
    for (int mi = 0; mi < 8; ++mi)
#pragma unroll
        for (int j = 0; j < 4; ++j) {
            float ps = 0.f;
#pragma unroll
            for (int oi = 0; oi < 4; ++oi) ps += acc[mi][oi][j] * wpf[oi];
            ps += __shfl_xor(ps, 1);
            ps += __shfl_xor(ps, 2);
            ps += __shfl_xor(ps, 4);
            ps += __shfl_xor(ps, 8);
            if (l15 == 0) partial[(mi * 16 + lg * 4 + j) * 4 + og] = ps;
        }
    __syncthreads();

    if (tid < 128) {
        float s = partial[tid * 4] + partial[tid * 4 + 1] + partial[tid * 4 + 2] +
                  partial[tid * 4 + 3] + bp[0];
        float p = 1.f / (1.f + __expf(-s));
        pv[tid] = p;
        size_t bi = (size_t)rb * BM + tid;
        out[EMB_ELEMS + bi * N_CON + n] = p;    // c_pred
    }
    __syncthreads();

#pragma unroll
    for (int mi = 0; mi < 8; ++mi)
#pragma unroll
        for (int oi = 0; oi < 2; ++oi)
#pragma unroll
            for (int j = 0; j < 4; ++j) {
                int row = mi * 16 + lg * 4 + j;
                int e = og * 32 + oi * 16 + l15;
                float p = pv[row];
                float v = acc[mi][oi][j] * p + acc[mi][oi + 2][j] * (1.f - p);
                size_t bi = (size_t)rb * BM + row;
                out[(bi * N_CON + n) * E_DIM + e] = v;
            }
}

// ---------------------------------------------------------------------------
// Fallback (no workspace): round-0 single-buffered fp32-staging kernel.
// ---------------------------------------------------------------------------
__global__ void __launch_bounds__(512, 4)
concept_fallback(const float* __restrict__ x,
                 const float* __restrict__ Wc,
                 const float* __restrict__ bc,
                 const float* __restrict__ wp,
                 const float* __restrict__ bp,
                 float* __restrict__ out) {
    __shared__ __align__(16) char smem[49152];
    char* ldsA = smem;
    char* ldsB = smem + 16384;

    const int tid  = threadIdx.x;
    const int wave = tid >> 6;
    const int lane = tid & 63;
    const int lg   = lane >> 4;
    const int l15  = lane & 15;
    const int h    = wave >> 2;
    const int og   = wave & 3;
    const int rb = blockIdx.x;
    const int n  = blockIdx.y;

    int otile[4];
#pragma unroll
    for (int oi = 0; oi < 4; ++oi) otile[oi] = og * 32 + (oi & 1) * 16 + (oi & 2) * 64;

    floatx4 acc[4][4];
#pragma unroll
    for (int mi = 0; mi < 4; ++mi)
#pragma unroll
        for (int oi = 0; oi < 4; ++oi) acc[mi][oi] = (floatx4){0.f, 0.f, 0.f, 0.f};

    const float* xg = x + (size_t)rb * BM * K_DIM;
    const float* wg = Wc + (size_t)n * K_DIM * TWO_E;

    for (int kt = 0; kt < K_DIM; kt += BK) {
#pragma unroll
        for (int it = 0; it < 2; ++it) {
            int s = it * 512 + tid;
            int r = s >> 3, g = s & 7;
            const float* p = xg + (size_t)r * K_DIM + kt + ((g ^ (r & 7)) * 8);
            floatx4 v0 = *(const floatx4*)p, v1 = *(const floatx4*)(p + 4);
            short8v b;
            b[0] = (short)bf16bits(v0[0]); b[1] = (short)bf16bits(v0[1]);
            b[2] = (short)bf16bits(v0[2]); b[3] = (short)bf16bits(v0[3]);
            b[4] = (short)bf16bits(v1[0]); b[5] = (short)bf16bits(v1[1]);
            b[6] = (short)bf16bits(v1[2]); b[7] = (short)bf16bits(v1[3]);
            *(short8v*)(ldsA + s * 16) = b;
        }
#pragma unroll
        for (int it = 0; it < 4; ++it) {
            int s = it * 512 + tid;
            int r = s >> 3, g = s & 7;
            int k0 = kt + (g ^ (r & 7)) * 8;
            short8v b;
#pragma unroll
            for (int j = 0; j < 8; ++j)
                b[j] = (short)bf16bits(wg[(size_t)(k0 + j) * TWO_E + r]);
            *(short8v*)(ldsB + s * 16) = b;
        }
        __syncthreads();

#pragma unroll
        for (int ks = 0; ks < 2; ++ks) {
            const int sw = ((ks * 4 + lg) ^ (l15 & 7)) * 16;
            short8v af[4], bfr[4];
#pragma unroll
            for (int mi = 0; mi < 4; ++mi)
                af[mi] = *(const short8v*)(ldsA + (h * 64 + mi * 16 + l15) * 128 + sw);
#pragma unroll
            for (int oi = 0; oi < 4; ++oi)
                bfr[oi] = *(const short8v*)(ldsB + (otile[oi] + l15) * 128 + sw);
#pragma unroll
            for (int mi = 0; mi < 4; ++mi)
#pragma unroll
                for (int oi = 0; oi < 4; ++oi)
                    acc[mi][oi] = __builtin_amdgcn_mfma_f32_16x16x32_bf16(
                        af[mi], bfr[oi], acc[mi][oi], 0, 0, 0);
        }
        __syncthreads();
    }

    float biasf[4], wpf[4];
#pragma unroll
    for (int oi = 0; oi < 4; ++oi) {
        int o = otile[oi] + l15;
        biasf[oi] = bc[n * TWO_E + o];
        wpf[oi]  = wp[o];
    }
#pragma unroll
    for (int mi = 0; mi < 4; ++mi)
#pragma unroll
        for (int oi = 0; oi < 4; ++oi)
#pragma unroll
            for (int j = 0; j < 4; ++j) {
                float v = acc[mi][oi][j] + biasf[oi];
                acc[mi][oi][j] = v >= 0.f ? v : 0.01f * v;
            }

    float* partial = (float*)smem;
    float* pv      = (float*)(smem + 2048);

#pragma unroll
    for (int mi = 0; mi < 4; ++mi)
#pragma unroll
        for (int j = 0; j < 4; ++j) {
            float ps = 0.f;
#pragma unroll
            for (int oi = 0; oi < 4; ++oi) ps += acc[mi][oi][j] * wpf[oi];
            ps += __shfl_xor(ps, 1);
            ps += __shfl_xor(ps, 2);
            ps += __shfl_xor(ps, 4);
            ps += __shfl_xor(ps, 8);
            if (l15 == 0) partial[(h * 64 + mi * 16 + lg * 4 + j) * 4 + og] = ps;
        }
    __syncthreads();

    if (tid < 128) {
        float s = partial[tid * 4] + partial[tid * 4 + 1] + partial[tid * 4 + 2] +
                  partial[tid * 4 + 3] + bp[0];
        float p = 1.f / (1.f + __expf(-s));
        pv[tid] = p;
        size_t bi = (size_t)rb * BM + tid;
        out[EMB_ELEMS + bi * N_CON + n] = p;
    }
    __syncthreads();

#pragma unroll
    for (int mi = 0; mi < 4; ++mi)
#pragma unroll
        for (int oi = 0; oi < 2; ++oi)
#pragma unroll
            for (int j = 0; j < 4; ++j) {
                int row = h * 64 + mi * 16 + lg * 4 + j;
                int e = og * 32 + oi * 16 + l15;
                float p = pv[row];
                float v = acc[mi][oi][j] * p + acc[mi][oi + 2][j] * (1.f - p);
                size_t bi = (size_t)rb * BM + row;
                out[(bi * N_CON + n) * E_DIM + e] = v;
            }
}

extern "C" void kernel_launch(void* const* d_in, const int* in_sizes, int n_in,
                              void* d_out, int out_size, void* d_ws, size_t ws_size,
                              hipStream_t stream) {
    const float* x  = (const float*)d_in[0];
    const float* Wc = (const float*)d_in[1];
    const float* bc = (const float*)d_in[2];
    const float* wp = (const float*)d_in[3];
    const float* bp = (const float*)d_in[4];
    float* out = (float*)d_out;

    if (ws_size >= WT_BYTES + XB_BYTES) {
        unsigned short* Wt = (unsigned short*)d_ws;
        unsigned short* xb = (unsigned short*)((char*)d_ws + WT_BYTES);
        prep<<<dim3(4, 16, 64), 256, 0, stream>>>(Wc, x, Wt, xb);
        concept6<<<dim3(16, 64), 256, 0, stream>>>(xb, Wt, bc, wp, bp, out);
    } else {
        concept_fallback<<<dim3(16, 64), 512, 0, stream>>>(
            x, Wc, bc, wp, bp, out);
    }
}

// Round 7
// 191.774 us; speedup vs baseline: 1.1073x; 1.1001x over previous
//
#include <hip/hip_runtime.h>
#include <hip/hip_bf16.h>

typedef __attribute__((ext_vector_type(8))) short short8v;
typedef __attribute__((ext_vector_type(4))) float floatx4;

#define B_ROWS 2048
#define K_DIM  1024
#define N_CON  64
#define TWO_E  256
#define E_DIM  128
#define BM     128
#define BK     64
#define LDSA_BYTES (BM * BK * 2)              // 16384
#define LDSB_BYTES (TWO_E * BK * 2)           // 32768
#define SMEM_BYTES (LDSA_BYTES + LDSB_BYTES)  // 49152
#define EMB_ELEMS 16777216ULL                 // 2048*64*128
#define WT_BYTES  33554432ULL                 // 64*256*1024*2
#define XB_BYTES  4194304ULL                  // 2048*1024*2

// fp32 -> bf16 bit pattern via proven __float2bfloat16 + memcpy punning.
static __device__ inline unsigned short bf16bits(float f) {
    __hip_bfloat16 h = __float2bfloat16(f);
    unsigned short u;
    __builtin_memcpy(&u, &h, 2);
    return u;
}

static __device__ inline unsigned int pack2(float lo, float hi) {
    return (unsigned int)bf16bits(lo) | ((unsigned int)bf16bits(hi) << 16);
}

// Async 16B global->LDS DMA. LDS dest = wave-uniform base + lane*16 (m104).
static __device__ inline void dma16(const void* g, void* l) {
    __builtin_amdgcn_global_load_lds(
        (const __attribute__((address_space(1))) unsigned int*)g,
        (__attribute__((address_space(3))) unsigned int*)l,
        16, 0, 0);
}

// ---------------------------------------------------------------------------
// prep2: W[n][k][o] fp32 -> Wt[n][o][k] bf16 (k-pair dword packing in LDS),
// x fp32 -> xb bf16. REWRITTEN for latency hiding:
//   grid 1024 = (n,ktile); each block does 4 ot-subtiles, software-pipelined:
//   subtile i+1's 4 float4 loads are issued BEFORE converting subtile i, and
//   the inter-phase barrier is a RAW s_barrier + lgkmcnt(0) (no vmcnt drain)
//   so the global prefetch stays in flight across it (the compiler inserts
//   the per-register vmcnt wait at first use, next iteration).
//   LDS double-buffered, stride-33 rows (conflict-free: bank = (c+j+kp+..)&31
//   bijective over the wave; old stride-36 was 8-way on write).
//   Transpose math identical to the verified prep (same Wt layout).
// ---------------------------------------------------------------------------
__global__ void __launch_bounds__(256) prep2(const float* __restrict__ W,
                                             const float* __restrict__ x,
                                             unsigned short* __restrict__ Wt,
                                             unsigned short* __restrict__ xb) {
    __shared__ unsigned int lds2[2][64 * 33];
    const int tid   = threadIdx.x;
    const int n     = blockIdx.x >> 4;
    const int ktile = blockIdx.x & 15;

    const float* srcn = W + ((size_t)n * K_DIM + (size_t)ktile * 64) * TWO_E;
    unsigned short* dstn = Wt + (size_t)n * TWO_E * K_DIM + (size_t)ktile * 64;

    const int kp = tid >> 4;          // 0..15
    const int c  = (tid & 15) * 4;    // o base within 64-wide subtile

    // cur / next register sets (named ping-pong — rule #20, no runtime index)
    floatx4 a00, a01, a10, a11;
    floatx4 b00, b01, b10, b11;

    {   // issue subtile 0 loads
        const float* src = srcn;      // ot = 0
        a00 = *(const floatx4*)&src[(size_t)(kp * 2) * TWO_E + c];
        a01 = *(const floatx4*)&src[(size_t)(kp * 2 + 1) * TWO_E + c];
        a10 = *(const floatx4*)&src[(size_t)(32 + kp * 2) * TWO_E + c];
        a11 = *(const floatx4*)&src[(size_t)(32 + kp * 2 + 1) * TWO_E + c];
    }

#pragma unroll
    for (int ot = 0; ot < 4; ++ot) {
        if (ot < 3) {                 // prefetch subtile ot+1 (compile-time)
            const float* src = srcn + (ot + 1) * 64;
            b00 = *(const floatx4*)&src[(size_t)(kp * 2) * TWO_E + c];
            b01 = *(const floatx4*)&src[(size_t)(kp * 2 + 1) * TWO_E + c];
            b10 = *(const floatx4*)&src[(size_t)(32 + kp * 2) * TWO_E + c];
            b11 = *(const floatx4*)&src[(size_t)(32 + kp * 2 + 1) * TWO_E + c];
        }
        unsigned int* buf = lds2[ot & 1];
        // convert cur -> LDS (k-pair packed dwords, stride-33 rows)
#pragma unroll
        for (int j = 0; j < 4; ++j) {
            buf[(c + j) * 33 + kp]      = pack2(a00[j], a01[j]);
            buf[(c + j) * 33 + 16 + kp] = pack2(a10[j], a11[j]);
        }
        // raw barrier: drain LDS writes, leave global prefetch in flight
        asm volatile("s_waitcnt lgkmcnt(0)" ::: "memory");
        __builtin_amdgcn_s_barrier();
        __builtin_amdgcn_sched_barrier(0);   // rule #18: pin reads below bar
        // LDS -> global, 16B per thread per it, coalesced 128B rows
        unsigned short* dst = dstn + (size_t)(ot * 64) * K_DIM;
#pragma unroll
        for (int it = 0; it < 2; ++it) {
            int q = it * 256 + tid;
            int o = q >> 3, kc = q & 7;
            short8v v = *(short8v*)&buf[o * 33 + kc * 4];
            *(short8v*)&dst[(size_t)o * K_DIM + kc * 8] = v;
        }
        // rotate (dead on last iter)
        a00 = b00; a01 = b01; a10 = b10; a11 = b11;
    }

    // ---- x convert: 2M elems over 1024 blocks, 8 per thread, 16B stores ----
    const size_t base = ((size_t)blockIdx.x * 256 + tid) * 8;
    floatx4 x0 = *(const floatx4*)&x[base];
    floatx4 x1 = *(const floatx4*)&x[base + 4];
    short8v xv;
    xv[0] = (short)bf16bits(x0[0]); xv[1] = (short)bf16bits(x0[1]);
    xv[2] = (short)bf16bits(x0[2]); xv[3] = (short)bf16bits(x0[3]);
    xv[4] = (short)bf16bits(x1[0]); xv[5] = (short)bf16bits(x1[1]);
    xv[6] = (short)bf16bits(x1[2]); xv[7] = (short)bf16bits(x1[3]);
    *(short8v*)&xb[base] = xv;
}

// ---------------------------------------------------------------------------
// Fused GEMM — byte-identical to round-4's verified concept4 (78.3-79.6 µs,
// 870 TF = the m97-structure ceiling; all schedule variants regressed).
//   WG = 256 threads (4 waves), tile 128 rows x 256 cols (one concept).
//   Wave-tile 128x64: acc[8][4], A/B fragments each read from LDS ONCE per
//   K-tile. Single 48KB LDS buffer, plain syncthreads loop. 2 WGs/CU.
//   T1 bijective XCD swizzle (FETCH 135->49 MB verified).
// ---------------------------------------------------------------------------
__global__ void __launch_bounds__(256, 2)
concept4(const unsigned short* __restrict__ xb,   // bf16 [2048][1024]
         const unsigned short* __restrict__ Wt,   // bf16 [n][o][k]
         const float* __restrict__ bc,
         const float* __restrict__ wp,
         const float* __restrict__ bp,
         float* __restrict__ out) {
    __shared__ __align__(16) char smem[SMEM_BYTES];
    char* ldsA = smem;
    char* ldsB = smem + LDSA_BYTES;

    const int tid  = threadIdx.x;
    const int wave = tid >> 6;        // 0..3 = o group
    const int lane = tid & 63;
    const int lg   = lane >> 4;       // quad 0..3
    const int l15  = lane & 15;
    const int og   = wave;

    // T1 bijective XCD swizzle over 1024 WGs (1024 % 8 == 0).
    const int lin = blockIdx.y * 16 + blockIdx.x;
    const int nid = (lin & 7) * 128 + (lin >> 3);
    const int rb  = nid & 15;         // 0..15 (128 rows each)
    const int n   = nid >> 4;         // 0..63

    int otile[4];
#pragma unroll
    for (int oi = 0; oi < 4; ++oi) otile[oi] = og * 32 + (oi & 1) * 16 + (oi & 2) * 64;

    floatx4 acc[8][4];
#pragma unroll
    for (int mi = 0; mi < 8; ++mi)
#pragma unroll
        for (int oi = 0; oi < 4; ++oi) acc[mi][oi] = (floatx4){0.f, 0.f, 0.f, 0.f};

    const unsigned short* xrow  = xb + (size_t)rb * BM * K_DIM;
    const unsigned short* wbase = Wt + (size_t)n * TWO_E * K_DIM;

    for (int kt = 0; kt < K_DIM; kt += BK) {
        // ---- stage A: 1024 granules (16KB), 4 waves x 4 chunks ----
#pragma unroll
        for (int it = 0; it < 4; ++it) {
            int c = it * 4 + wave;
            int s = c * 64 + lane;
            int r = s >> 3, g = s & 7;
            dma16(xrow + (size_t)r * K_DIM + kt + ((g ^ (r & 7)) * 8),
                  ldsA + c * 1024);
        }
        // ---- stage B: 2048 granules (32KB), 4 waves x 8 chunks ----
#pragma unroll
        for (int it = 0; it < 8; ++it) {
            int c = it * 4 + wave;
            int s = c * 64 + lane;
            int r = s >> 3, g = s & 7;
            dma16(wbase + (size_t)r * K_DIM + kt + ((g ^ (r & 7)) * 8),
                  ldsB + c * 1024);
        }
        __syncthreads();   // compiler drains vmcnt(0) here — validates DMA

        // ---- compute: quadrant ordering, every fragment read once ----
        short8v afA[4][2], afB[4][2], bf[2][2], bf2[2][2];

        // Q1: A rows 0-63 + B cols oi0,1
#pragma unroll
        for (int ks = 0; ks < 2; ++ks) {
            const int sw = ((ks * 4 + lg) ^ (l15 & 7)) * 16;
#pragma unroll
            for (int mi = 0; mi < 4; ++mi)
                afA[mi][ks] = *(const short8v*)(ldsA + (mi * 16 + l15) * 128 + sw);
#pragma unroll
            for (int oi = 0; oi < 2; ++oi)
                bf[oi][ks] = *(const short8v*)(ldsB + (otile[oi] + l15) * 128 + sw);
        }
#pragma unroll
        for (int mi = 0; mi < 4; ++mi)
#pragma unroll
            for (int oi = 0; oi < 2; ++oi)
#pragma unroll
                for (int ks = 0; ks < 2; ++ks)
                    acc[mi][oi] = __builtin_amdgcn_mfma_f32_16x16x32_bf16(
                        afA[mi][ks], bf[oi][ks], acc[mi][oi], 0, 0, 0);

        // Q2: B cols oi2,3 (A rows 0-63 reused from regs)
#pragma unroll
        for (int ks = 0; ks < 2; ++ks) {
            const int sw = ((ks * 4 + lg) ^ (l15 & 7)) * 16;
#pragma unroll
            for (int oi = 0; oi < 2; ++oi)
                bf2[oi][ks] = *(const short8v*)(ldsB + (otile[2 + oi] + l15) * 128 + sw);
        }
#pragma unroll
        for (int mi = 0; mi < 4; ++mi)
#pragma unroll
            for (int oi = 0; oi < 2; ++oi)
#pragma unroll
                for (int ks = 0; ks < 2; ++ks)
                    acc[mi][2 + oi] = __builtin_amdgcn_mfma_f32_16x16x32_bf16(
                        afA[mi][ks], bf2[oi][ks], acc[mi][2 + oi], 0, 0, 0);

        // Q3: A rows 64-127 (B cols oi2,3 reused from regs)
#pragma unroll
        for (int ks = 0; ks < 2; ++ks) {
            const int sw = ((ks * 4 + lg) ^ (l15 & 7)) * 16;
#pragma unroll
            for (int mi = 0; mi < 4; ++mi)
                afB[mi][ks] = *(const short8v*)(ldsA + (64 + mi * 16 + l15) * 128 + sw);
        }
#pragma unroll
        for (int mi = 0; mi < 4; ++mi)
#pragma unroll
            for (int oi = 0; oi < 2; ++oi)
#pragma unroll
                for (int ks = 0; ks < 2; ++ks)
                    acc[4 + mi][2 + oi] = __builtin_amdgcn_mfma_f32_16x16x32_bf16(
                        afB[mi][ks], bf2[oi][ks], acc[4 + mi][2 + oi], 0, 0, 0);

        // Q4: A rows 64-127 x B cols oi0,1 (both reused from regs)
#pragma unroll
        for (int mi = 0; mi < 4; ++mi)
#pragma unroll
            for (int oi = 0; oi < 2; ++oi)
#pragma unroll
                for (int ks = 0; ks < 2; ++ks)
                    acc[4 + mi][oi] = __builtin_amdgcn_mfma_f32_16x16x32_bf16(
                        afB[mi][ks], bf[oi][ks], acc[4 + mi][oi], 0, 0, 0);

        __syncthreads();   // protect buffer before next stage overwrites
    }

    // ---- epilogue (fp32) ----
    float biasf[4], wpf[4];
#pragma unroll
    for (int oi = 0; oi < 4; ++oi) {
        int o = otile[oi] + l15;
        biasf[oi] = bc[n * TWO_E + o];
        wpf[oi]  = wp[o];
    }
#pragma unroll
    for (int mi = 0; mi < 8; ++mi)
#pragma unroll
        for (int oi = 0; oi < 4; ++oi)
#pragma unroll
            for (int j = 0; j < 4; ++j) {
                float v = acc[mi][oi][j] + biasf[oi];
                acc[mi][oi][j] = v >= 0.f ? v : 0.01f * v;   // LeakyReLU
            }

    float* partial = (float*)smem;            // [128][4]
    float* pv      = (float*)(smem + 2048);   // [128]

#pragma unroll
    for (int mi = 0; mi < 8; ++mi)
#pragma unroll
        for (int j = 0; j < 4; ++j) {
            float ps = 0.f;
#pragma unroll
            for (int oi = 0; oi < 4; ++oi) ps += acc[mi][oi][j] * wpf[oi];
            ps += __shfl_xor(ps, 1);
            ps += __shfl_xor(ps, 2);
            ps += __shfl_xor(ps, 4);
            ps += __shfl_xor(ps, 8);
            if (l15 == 0) partial[(mi * 16 + lg * 4 + j) * 4 + og] = ps;
        }
    __syncthreads();

    if (tid < 128) {
        float s = partial[tid * 4] + partial[tid * 4 + 1] + partial[tid * 4 + 2] +
                  partial[tid * 4 + 3] + bp[0];
        float p = 1.f / (1.f + __expf(-s));
        pv[tid] = p;
        size_t bi = (size_t)rb * BM + tid;
        out[EMB_ELEMS + bi * N_CON + n] = p;    // c_pred
    }
    __syncthreads();

#pragma unroll
    for (int mi = 0; mi < 8; ++mi)
#pragma unroll
        for (int oi = 0; oi < 2; ++oi)
#pragma unroll
            for (int j = 0; j < 4; ++j) {
                int row = mi * 16 + lg * 4 + j;
                int e = og * 32 + oi * 16 + l15;
                float p = pv[row];
                float v = acc[mi][oi][j] * p + acc[mi][oi + 2][j] * (1.f - p);
                size_t bi = (size_t)rb * BM + row;
                out[(bi * N_CON + n) * E_DIM + e] = v;
            }
}

// ---------------------------------------------------------------------------
// Fallback (no workspace): round-0 single-buffered fp32-staging kernel.
// ---------------------------------------------------------------------------
__global__ void __launch_bounds__(512, 4)
concept_fallback(const float* __restrict__ x,
                 const float* __restrict__ Wc,
                 const float* __restrict__ bc,
                 const float* __restrict__ wp,
                 const float* __restrict__ bp,
                 float* __restrict__ out) {
    __shared__ __align__(16) char smem[SMEM_BYTES];
    char* ldsA = smem;
    char* ldsB = smem + LDSA_BYTES;

    const int tid  = threadIdx.x;
    const int wave = tid >> 6;
    const int lane = tid & 63;
    const int lg   = lane >> 4;
    const int l15  = lane & 15;
    const int h    = wave >> 2;
    const int og   = wave & 3;
    const int rb = blockIdx.x;
    const int n  = blockIdx.y;

    int otile[4];
#pragma unroll
    for (int oi = 0; oi < 4; ++oi) otile[oi] = og * 32 + (oi & 1) * 16 + (oi & 2) * 64;

    floatx4 acc[4][4];
#pragma unroll
    for (int mi = 0; mi < 4; ++mi)
#pragma unroll
        for (int oi = 0; oi < 4; ++oi) acc[mi][oi] = (floatx4){0.f, 0.f, 0.f, 0.f};

    const float* xg = x + (size_t)rb * BM * K_DIM;
    const float* wg = Wc + (size_t)n * K_DIM * TWO_E;

    for (int kt = 0; kt < K_DIM; kt += BK) {
#pragma unroll
        for (int it = 0; it < 2; ++it) {
            int s = it * 512 + tid;
            int r = s >> 3, g = s & 7;
            const float* p = xg + (size_t)r * K_DIM + kt + ((g ^ (r & 7)) * 8);
            floatx4 v0 = *(const floatx4*)p, v1 = *(const floatx4*)(p + 4);
            short8v b;
            b[0] = (short)bf16bits(v0[0]); b[1] = (short)bf16bits(v0[1]);
            b[2] = (short)bf16bits(v0[2]); b[3] = (short)bf16bits(v0[3]);
            b[4] = (short)bf16bits(v1[0]); b[5] = (short)bf16bits(v1[1]);
            b[6] = (short)bf16bits(v1[2]); b[7] = (short)bf16bits(v1[3]);
            *(short8v*)(ldsA + s * 16) = b;
        }
#pragma unroll
        for (int it = 0; it < 4; ++it) {
            int s = it * 512 + tid;
            int r = s >> 3, g = s & 7;
            int k0 = kt + (g ^ (r & 7)) * 8;
            short8v b;
#pragma unroll
            for (int j = 0; j < 8; ++j)
                b[j] = (short)bf16bits(wg[(size_t)(k0 + j) * TWO_E + r]);
            *(short8v*)(ldsB + s * 16) = b;
        }
        __syncthreads();

#pragma unroll
        for (int ks = 0; ks < 2; ++ks) {
            const int sw = ((ks * 4 + lg) ^ (l15 & 7)) * 16;
            short8v af[4], bfr[4];
#pragma unroll
            for (int mi = 0; mi < 4; ++mi)
                af[mi] = *(const short8v*)(ldsA + (h * 64 + mi * 16 + l15) * 128 + sw);
#pragma unroll
            for (int oi = 0; oi < 4; ++oi)
                bfr[oi] = *(const short8v*)(ldsB + (otile[oi] + l15) * 128 + sw);
#pragma unroll
            for (int mi = 0; mi < 4; ++mi)
#pragma unroll
                for (int oi = 0; oi < 4; ++oi)
                    acc[mi][oi] = __builtin_amdgcn_mfma_f32_16x16x32_bf16(
                        af[mi], bfr[oi], acc[mi][oi], 0, 0, 0);
        }
        __syncthreads();
    }

    float biasf[4], wpf[4];
#pragma unroll
    for (int oi = 0; oi < 4; ++oi) {
        int o = otile[oi] + l15;
        biasf[oi] = bc[n * TWO_E + o];
        wpf[oi]  = wp[o];
    }
#pragma unroll
    for (int mi = 0; mi < 4; ++mi)
#pragma unroll
        for (int oi = 0; oi < 4; ++oi)
#pragma unroll
            for (int j = 0; j < 4; ++j) {
                float v = acc[mi][oi][j] + biasf[oi];
                acc[mi][oi][j] = v >= 0.f ? v : 0.01f * v;
            }

    float* partial = (float*)smem;
    float* pv      = (float*)(smem + 2048);

#pragma unroll
    for (int mi = 0; mi < 4; ++mi)
#pragma unroll
        for (int j = 0; j < 4; ++j) {
            float ps = 0.f;
#pragma unroll
            for (int oi = 0; oi < 4; ++oi) ps += acc[mi][oi][j] * wpf[oi];
            ps += __shfl_xor(ps, 1);
            ps += __shfl_xor(ps, 2);
            ps += __shfl_xor(ps, 4);
            ps += __shfl_xor(ps, 8);
            if (l15 == 0) partial[(h * 64 + mi * 16 + lg * 4 + j) * 4 + og] = ps;
        }
    __syncthreads();

    if (tid < 128) {
        float s = partial[tid * 4] + partial[tid * 4 + 1] + partial[tid * 4 + 2] +
                  partial[tid * 4 + 3] + bp[0];
        float p = 1.f / (1.f + __expf(-s));
        pv[tid] = p;
        size_t bi = (size_t)rb * BM + tid;
        out[EMB_ELEMS + bi * N_CON + n] = p;
    }
    __syncthreads();

#pragma unroll
    for (int mi = 0; mi < 4; ++mi)
#pragma unroll
        for (int oi = 0; oi < 2; ++oi)
#pragma unroll
            for (int j = 0; j < 4; ++j) {
                int row = h * 64 + mi * 16 + lg * 4 + j;
                int e = og * 32 + oi * 16 + l15;
                float p = pv[row];
                float v = acc[mi][oi][j] * p + acc[mi][oi + 2][j] * (1.f - p);
                size_t bi = (size_t)rb * BM + row;
                out[(bi * N_CON + n) * E_DIM + e] = v;
            }
}

extern "C" void kernel_launch(void* const* d_in, const int* in_sizes, int n_in,
                              void* d_out, int out_size, void* d_ws, size_t ws_size,
                              hipStream_t stream) {
    const float* x  = (const float*)d_in[0];
    const float* Wc = (const float*)d_in[1];
    const float* bc = (const float*)d_in[2];
    const float* wp = (const float*)d_in[3];
    const float* bp = (const float*)d_in[4];
    float* out = (float*)d_out;

    if (ws_size >= WT_BYTES + XB_BYTES) {
        unsigned short* Wt = (unsigned short*)d_ws;
        unsigned short* xb = (unsigned short*)((char*)d_ws + WT_BYTES);
        prep2<<<dim3(1024), 256, 0, stream>>>(Wc, x, Wt, xb);
        concept4<<<dim3(16, 64), 256, 0, stream>>>(xb, Wt, bc, wp, bp, out);
    } else {
        concept_fallback<<<dim3(16, 64), 512, 0, stream>>>(
            x, Wc, bc, wp, bp, out);
    }
}